// Round 4
// baseline (314.423 us; speedup 1.0000x reference)
//
#include <hip/hip_runtime.h>
#include <math.h>

#define BATCH 16
#define CDIM 256
#define HW 9216
#define RDIM 32
#define SPLITS 16
#define KSLAB (HW / SPLITS)   /* 576 */
#define KCH 64                /* k-columns staged per chunk (gram) */
#define NCHUNK (KSLAB / KCH)  /* 9 */

#define BN 256                /* out_kernel n-tile */
#define BK 64                 /* out_kernel k-chunk */
#define BOFF 32768            /* ldsB byte offset inside shared block */

typedef __attribute__((ext_vector_type(8))) short short8;
typedef __attribute__((ext_vector_type(4))) short short4_t;
typedef __attribute__((ext_vector_type(4))) float f32x4;

__device__ __forceinline__ unsigned short bf16_rne(float x) {
    union { float f; unsigned u; } a; a.f = x;
    return (unsigned short)((a.u + 0x7fffu + ((a.u >> 16) & 1u)) >> 16);
}
__device__ __forceinline__ float bf16_to_f(unsigned short h) {
    union { unsigned u; float f; } a; a.u = ((unsigned)h) << 16;
    return a.f;
}
__device__ __forceinline__ unsigned pack2(float lo, float hi) {
    return (unsigned)bf16_rne(lo) | ((unsigned)bf16_rne(hi) << 16);
}

__device__ __forceinline__ int swzidx(int row, int k) {
    int byte = row * 128 + k * 2;
    byte ^= ((row & 7) << 4) ^ ((row & 8) << 1);
    return byte >> 1;
}
__device__ __forceinline__ int bofs(int row, int k) {
    return (((row) << 7) | ((k) << 1)) ^ (((row ^ (row >> 2)) & 7) << 4);
}

// ---------------- K1: energy partial = v v^T (split-K, bf16 hi/lo MFMA) ----------
// ATOMIC=false: store partials to part[split]; ATOMIC=true: atomicAdd into energy.
// Prefetch: chunk ch+1's global loads issue before chunk ch's MFMAs.
template <bool ATOMIC>
__global__ __launch_bounds__(1024) void gram_kernel(const float* __restrict__ x,
                                                    float* __restrict__ epart,
                                                    float* __restrict__ pooled) {
    int split = blockIdx.x;
    int b     = blockIdx.y;
    const float* v = x + (size_t)b * CDIM * HW;
    int kbase0 = split * KSLAB;

    __shared__ short ldsH[CDIM * KCH];   // 32 KB
    __shared__ short ldsL[CDIM * KCH];   // 32 KB

    int t    = threadIdx.x;
    int row  = t >> 2;
    int kq   = t & 3;
    int lane = t & 63;
    int wave = t >> 6;
    int wr   = wave >> 2, wc = wave & 3;
    int lhi  = lane >> 4;
    int llo  = lane & 15;

    const float4* vrow = (const float4*)(v + (size_t)row * HW);

    f32x4 acc[4][4];
    #pragma unroll
    for (int i = 0; i < 4; ++i)
        #pragma unroll
        for (int j = 0; j < 4; ++j)
            acc[i][j] = (f32x4){0.f, 0.f, 0.f, 0.f};

    float psum = 0.f;
    float4 f[4];

    // preload chunk 0
    #pragma unroll
    for (int s = 0; s < 4; ++s) f[s] = vrow[(kbase0 >> 2) + kq * 4 + s];

    for (int ch = 0; ch < NCHUNK; ++ch) {
        #pragma unroll
        for (int s = 0; s < 4; ++s) psum += f[s].x + f[s].y + f[s].z + f[s].w;

        short8 h8[2], l8[2];
        #pragma unroll
        for (int g = 0; g < 2; ++g) {
            float vals[8] = { f[2*g].x, f[2*g].y, f[2*g].z, f[2*g].w,
                              f[2*g+1].x, f[2*g+1].y, f[2*g+1].z, f[2*g+1].w };
            #pragma unroll
            for (int j = 0; j < 8; ++j) {
                unsigned short h = bf16_rne(vals[j]);
                float rem = vals[j] - bf16_to_f(h);
                h8[g][j] = (short)h;
                l8[g][j] = (short)bf16_rne(rem);
            }
        }
        __syncthreads();   // previous chunk's readers done
        #pragma unroll
        for (int g = 0; g < 2; ++g) {
            int idx = swzidx(row, kq * 16 + g * 8);
            *(short8*)&ldsH[idx] = h8[g];
            *(short8*)&ldsL[idx] = l8[g];
        }
        __syncthreads();   // tile staged

        // prefetch next chunk under the MFMAs
        if (ch + 1 < NCHUNK) {
            int kb = kbase0 + (ch + 1) * KCH;
            #pragma unroll
            for (int s = 0; s < 4; ++s) f[s] = vrow[(kb >> 2) + kq * 4 + s];
        }

        #pragma unroll
        for (int ks = 0; ks < 2; ++ks) {
            int kf = ks * 32 + lhi * 8;
            short8 Ah[4], Al[4], Bh[4], Bl[4];
            #pragma unroll
            for (int rb = 0; rb < 4; ++rb) {
                int idx = swzidx(wr * 64 + rb * 16 + llo, kf);
                Ah[rb] = *(const short8*)&ldsH[idx];
                Al[rb] = *(const short8*)&ldsL[idx];
            }
            #pragma unroll
            for (int cb = 0; cb < 4; ++cb) {
                int idx = swzidx(wc * 64 + cb * 16 + llo, kf);
                Bh[cb] = *(const short8*)&ldsH[idx];
                Bl[cb] = *(const short8*)&ldsL[idx];
            }
            #pragma unroll
            for (int rb = 0; rb < 4; ++rb)
                #pragma unroll
                for (int cb = 0; cb < 4; ++cb) {
                    acc[rb][cb] = __builtin_amdgcn_mfma_f32_16x16x32_bf16(Ah[rb], Bh[cb], acc[rb][cb], 0, 0, 0);
                    acc[rb][cb] = __builtin_amdgcn_mfma_f32_16x16x32_bf16(Ah[rb], Bl[cb], acc[rb][cb], 0, 0, 0);
                    acc[rb][cb] = __builtin_amdgcn_mfma_f32_16x16x32_bf16(Al[rb], Bh[cb], acc[rb][cb], 0, 0, 0);
                }
        }
    }

    psum += __shfl_xor(psum, 1);
    psum += __shfl_xor(psum, 2);
    if (kq == 0) atomicAdd(&pooled[b * CDIM + row], psum);

    if (ATOMIC) {
        #pragma unroll
        for (int rb = 0; rb < 4; ++rb) {
            int r0 = wr * 64 + rb * 16 + lhi * 4;
            #pragma unroll
            for (int cb = 0; cb < 4; ++cb) {
                int c0 = wc * 64 + cb * 16 + llo;
                #pragma unroll
                for (int reg = 0; reg < 4; ++reg)
                    atomicAdd(&epart[((size_t)b * CDIM + r0 + reg) * CDIM + c0], acc[rb][cb][reg]);
            }
        }
    } else {
        float* pb = epart + ((size_t)split * BATCH + b) * CDIM * CDIM;
        #pragma unroll
        for (int rb = 0; rb < 4; ++rb) {
            int r0 = wr * 64 + rb * 16 + lhi * 4;
            #pragma unroll
            for (int cb = 0; cb < 4; ++cb) {
                int c0 = wc * 64 + cb * 16 + llo;
                #pragma unroll
                for (int reg = 0; reg < 4; ++reg)
                    pb[(size_t)(r0 + reg) * CDIM + c0] = acc[rb][cb][reg];
            }
        }
    }
}

// ---------------- K2: SE MLP -> sigmoid gate ----------------
__global__ __launch_bounds__(256) void se_kernel(const float* __restrict__ pooled,
                                                 const float* __restrict__ w1,
                                                 const float* __restrict__ b1,
                                                 const float* __restrict__ w2,
                                                 const float* __restrict__ b2,
                                                 float* __restrict__ gate) {
    int b = blockIdx.x;
    int t = threadIdx.x;
    __shared__ float p[CDIM];
    __shared__ float hid[RDIM];
    p[t] = pooled[b * CDIM + t] * (1.0f / HW);
    __syncthreads();
    if (t < RDIM) {
        float s = b1[t];
        const float* wr = w1 + t * CDIM;
        for (int k = 0; k < CDIM; ++k) s = fmaf(wr[k], p[k], s);
        hid[t] = s > 0.f ? s : 0.f;
    }
    __syncthreads();
    float s = b2[t];
    const float* wr = w2 + t * RDIM;
    #pragma unroll
    for (int k = 0; k < RDIM; ++k) s = fmaf(wr[k], hid[k], s);
    gate[b * CDIM + t] = 1.0f / (1.0f + expf(-s));
}

// ---------------- K3: reduce NS split-partials + row softmax ----------------
// att[row][d] = exp(rowmin - e[row][d]) / sum, e = sum of NS partials.
template <int NS>
__global__ __launch_bounds__(256) void softmax_kernel(const float* __restrict__ src,
                                                      float* __restrict__ att) {
    int row = blockIdx.x;              // b*C + c
    int t = threadIdx.x;
    const float* s0 = src + (size_t)row * CDIM + t;
    float val = 0.f;
    #pragma unroll
    for (int s = 0; s < NS; ++s)
        val += s0[(size_t)s * BATCH * CDIM * CDIM];

    float m = val;
    for (int off = 32; off > 0; off >>= 1) m = fminf(m, __shfl_down(m, off));
    __shared__ float redm[4];
    if ((t & 63) == 0) redm[t >> 6] = m;
    __syncthreads();
    float rowmin = fminf(fminf(redm[0], redm[1]), fminf(redm[2], redm[3]));

    float p = expf(rowmin - val);
    float s = p;
    for (int off = 32; off > 0; off >>= 1) s += __shfl_down(s, off);
    __shared__ float reds[4];
    if ((t & 63) == 0) reds[t >> 6] = s;
    __syncthreads();
    float tot = reds[0] + reds[1] + reds[2] + reds[3];
    att[(size_t)row * CDIM + t] = p / tot;
}

// ---------------- K4: out = gamma * gate * (att @ v) + x  (bf16 MFMA) ----------
__global__ __launch_bounds__(1024) void out_kernel(const float* __restrict__ att,
                                                   const float* __restrict__ x,
                                                   const float* __restrict__ gate,
                                                   const float* __restrict__ gammap,
                                                   float* __restrict__ out) {
    __shared__ __align__(16) char lds[65536];   // A: 32KB @0, B: 32KB @BOFF

    const int t    = threadIdx.x;
    const int lane = t & 63;
    const int wave = t >> 6;
    const int wr   = wave >> 2, wc = wave & 3;
    const int lhi  = lane >> 4, llo = lane & 15;
    const int nblk = blockIdx.x * BN;
    const int b    = blockIdx.y;

    const float* v    = x   + (size_t)b * CDIM * HW;
    const float* attb = att + (size_t)b * CDIM * CDIM;

    f32x4 acc[4][4];
    #pragma unroll
    for (int i = 0; i < 4; ++i)
        #pragma unroll
        for (int j = 0; j < 4; ++j)
            acc[i][j] = (f32x4){0.f, 0.f, 0.f, 0.f};

    float4 va0[2], va1[2], aa[4];

    auto load_chunk = [&](int k0) {
        #pragma unroll
        for (int i = 0; i < 2; ++i) {
            int dd0 = 2 * (wave + 16 * i);
            const float* r0 = v + (size_t)(k0 + dd0) * HW + nblk + lane * 4;
            va0[i] = *(const float4*)r0;
            va1[i] = *(const float4*)(r0 + HW);
        }
        #pragma unroll
        for (int i = 0; i < 4; ++i) {
            int c = (t >> 4) + 64 * i;
            aa[i] = *(const float4*)&attb[(size_t)c * CDIM + k0 + (t & 15) * 4];
        }
    };

    load_chunk(0);

    for (int ch = 0; ch < 4; ++ch) {
        __syncthreads();
        #pragma unroll
        for (int i = 0; i < 2; ++i) {
            int dd0 = 2 * (wave + 16 * i);
            const float* f0 = (const float*)&va0[i];
            const float* f1 = (const float*)&va1[i];
            #pragma unroll
            for (int j = 0; j < 4; ++j) {
                int n = lane * 4 + j;
                *(unsigned*)(lds + BOFF + bofs(n, dd0)) = pack2(f0[j], f1[j]);
            }
        }
        #pragma unroll
        for (int i = 0; i < 4; ++i) {
            int c = (t >> 4) + 64 * i;
            const float* fa = (const float*)&aa[i];
            short4_t h = { (short)bf16_rne(fa[0]), (short)bf16_rne(fa[1]),
                           (short)bf16_rne(fa[2]), (short)bf16_rne(fa[3]) };
            *(short4_t*)(lds + bofs(c, (t & 15) * 4)) = h;
        }
        __syncthreads();

        if (ch < 3) load_chunk((ch + 1) * BK);

        #pragma unroll
        for (int ks = 0; ks < 2; ++ks) {
            int kb = ks * 32 + lhi * 8;
            short8 Af[4], Bf[4];
            #pragma unroll
            for (int rb = 0; rb < 4; ++rb)
                Af[rb] = *(const short8*)(lds + bofs(wr * 64 + rb * 16 + llo, kb));
            #pragma unroll
            for (int cb = 0; cb < 4; ++cb)
                Bf[cb] = *(const short8*)(lds + BOFF + bofs(wc * 64 + cb * 16 + llo, kb));
            #pragma unroll
            for (int rb = 0; rb < 4; ++rb)
                #pragma unroll
                for (int cb = 0; cb < 4; ++cb)
                    acc[rb][cb] = __builtin_amdgcn_mfma_f32_16x16x32_bf16(Af[rb], Bf[cb], acc[rb][cb], 0, 0, 0);
        }
    }

    float gm = gammap[0];
    #pragma unroll
    for (int rb = 0; rb < 4; ++rb) {
        #pragma unroll
        for (int r = 0; r < 4; ++r) {
            int c = wr * 64 + rb * 16 + lhi * 4 + r;
            float g = gm * gate[b * CDIM + c];
            size_t rowbase = ((size_t)b * CDIM + c) * HW + nblk;
            #pragma unroll
            for (int cb = 0; cb < 4; ++cb) {
                int n = wc * 64 + cb * 16 + llo;
                out[rowbase + n] = fmaf(acc[rb][cb][r], g, x[rowbase + n]);
            }
        }
    }
}

extern "C" void kernel_launch(void* const* d_in, const int* in_sizes, int n_in,
                              void* d_out, int out_size, void* d_ws, size_t ws_size,
                              hipStream_t stream) {
    const float* x     = (const float*)d_in[0];
    const float* gamma = (const float*)d_in[1];
    const float* w1    = (const float*)d_in[2];
    const float* b1    = (const float*)d_in[3];
    const float* w2    = (const float*)d_in[4];
    const float* b2    = (const float*)d_in[5];
    float* out = (float*)d_out;

    const size_t attElems  = (size_t)BATCH * CDIM * CDIM;          // 1 Mi floats
    const size_t partElems = (size_t)SPLITS * attElems;            // 16 Mi floats
    const size_t needPart  = (partElems + attElems + 2 * BATCH * CDIM) * sizeof(float);

    if (ws_size >= needPart) {
        // ---- no-atomic path: per-split partials, reduced inside softmax ----
        float* part   = (float*)d_ws;
        float* att    = part + partElems;
        float* pooled = att + attElems;
        float* gate   = pooled + BATCH * CDIM;

        hipMemsetAsync(pooled, 0, (size_t)BATCH * CDIM * sizeof(float), stream);
        gram_kernel<false><<<dim3(SPLITS, BATCH), 1024, 0, stream>>>(x, part, pooled);
        se_kernel<<<BATCH, 256, 0, stream>>>(pooled, w1, b1, w2, b2, gate);
        softmax_kernel<SPLITS><<<BATCH * CDIM, 256, 0, stream>>>(part, att);
        out_kernel<<<dim3(HW / BN, BATCH), 1024, 0, stream>>>(att, x, gate, gamma, out);
    } else {
        // ---- fallback: atomic accumulation into one energy buffer ----
        float* energy = (float*)d_ws;
        float* pooled = energy + attElems;
        float* gate   = pooled + BATCH * CDIM;

        hipMemsetAsync(energy, 0, attElems * sizeof(float), stream);
        hipMemsetAsync(pooled, 0, (size_t)BATCH * CDIM * sizeof(float), stream);
        gram_kernel<true><<<dim3(SPLITS, BATCH), 1024, 0, stream>>>(x, energy, pooled);
        se_kernel<<<BATCH, 256, 0, stream>>>(pooled, w1, b1, w2, b2, gate);
        softmax_kernel<1><<<BATCH * CDIM, 256, 0, stream>>>(energy, energy);
        out_kernel<<<dim3(HW / BN, BATCH), 1024, 0, stream>>>(energy, x, gate, gamma, out);
    }
}

// Round 5
// 261.654 us; speedup vs baseline: 1.2017x; 1.2017x over previous
//
#include <hip/hip_runtime.h>
#include <math.h>

#define BATCH 16
#define CDIM 256
#define HW 9216
#define RDIM 32
#define SPLITS 16
#define KSLAB (HW / SPLITS)   /* 576 */
#define KCH 64                /* k-columns staged per chunk (gram) */
#define NCHUNK (KSLAB / KCH)  /* 9 */

#define BN 256                /* out_kernel n-tile */
#define BK 64                 /* out_kernel k-chunk */
#define BOFF 32768            /* ldsB byte offset inside shared block */

typedef __attribute__((ext_vector_type(8))) short short8;
typedef __attribute__((ext_vector_type(4))) short short4_t;
typedef __attribute__((ext_vector_type(4))) float f32x4;

__device__ __forceinline__ unsigned short bf16_rne(float x) {
    union { float f; unsigned u; } a; a.f = x;
    return (unsigned short)((a.u + 0x7fffu + ((a.u >> 16) & 1u)) >> 16);
}
__device__ __forceinline__ float bf16_to_f(unsigned short h) {
    union { unsigned u; float f; } a; a.u = ((unsigned)h) << 16;
    return a.f;
}
__device__ __forceinline__ unsigned pack2(float lo, float hi) {
    return (unsigned)bf16_rne(lo) | ((unsigned)bf16_rne(hi) << 16);
}

__device__ __forceinline__ int swzidx(int row, int k) {
    int byte = row * 128 + k * 2;
    byte ^= ((row & 7) << 4) ^ ((row & 8) << 1);
    return byte >> 1;
}
__device__ __forceinline__ int bofs(int row, int k) {
    return (((row) << 7) | ((k) << 1)) ^ (((row ^ (row >> 2)) & 7) << 4);
}

// ---------------- K1: energy = v v^T (split-K, bf16 hi/lo MFMA) ----------
// Double-buffered LDS, ONE barrier per chunk: iteration i+1 writes buf[p^1],
// last read in iteration i-1's MFMA phase -- every wave passed barrier i
// (program-order after its own i-1 MFMA reads + lgkmcnt drain) before any
// wave can reach iteration i+1's writes. Loads for ch+1 issue pre-barrier
// and drain under the next convert. Atomic fp32 epilogue into energy.
__global__ __launch_bounds__(1024) void gram_kernel(const float* __restrict__ x,
                                                    float* __restrict__ energy,
                                                    float* __restrict__ pooled) {
    int split = blockIdx.x;
    int b     = blockIdx.y;
    const float* v = x + (size_t)b * CDIM * HW;
    int kbase0 = split * KSLAB;

    __shared__ short ldsH[2][CDIM * KCH];   // 2 x 32 KB
    __shared__ short ldsL[2][CDIM * KCH];   // 2 x 32 KB

    int t    = threadIdx.x;
    int row  = t >> 2;
    int kq   = t & 3;
    int lane = t & 63;
    int wave = t >> 6;
    int wr   = wave >> 2, wc = wave & 3;
    int lhi  = lane >> 4;
    int llo  = lane & 15;

    const float4* vrow = (const float4*)(v + (size_t)row * HW);

    f32x4 acc[4][4];
    #pragma unroll
    for (int i = 0; i < 4; ++i)
        #pragma unroll
        for (int j = 0; j < 4; ++j)
            acc[i][j] = (f32x4){0.f, 0.f, 0.f, 0.f};

    float psum = 0.f;
    float4 f[4];

    // preload chunk 0
    #pragma unroll
    for (int s = 0; s < 4; ++s) f[s] = vrow[(kbase0 >> 2) + kq * 4 + s];

    for (int ch = 0; ch < NCHUNK; ++ch) {
        int p = ch & 1;
        short* bH = (short*)ldsH[p];
        short* bL = (short*)ldsL[p];

        // ---- convert staged regs (waits vmcnt) ----
        #pragma unroll
        for (int s = 0; s < 4; ++s) psum += f[s].x + f[s].y + f[s].z + f[s].w;

        short8 h8[2], l8[2];
        #pragma unroll
        for (int g = 0; g < 2; ++g) {
            float vals[8] = { f[2*g].x, f[2*g].y, f[2*g].z, f[2*g].w,
                              f[2*g+1].x, f[2*g+1].y, f[2*g+1].z, f[2*g+1].w };
            #pragma unroll
            for (int j = 0; j < 8; ++j) {
                unsigned short h = bf16_rne(vals[j]);
                float rem = vals[j] - bf16_to_f(h);
                h8[g][j] = (short)h;
                l8[g][j] = (short)bf16_rne(rem);
            }
        }
        // ---- write to buffer p ----
        #pragma unroll
        for (int g = 0; g < 2; ++g) {
            int idx = swzidx(row, kq * 16 + g * 8);
            *(short8*)&bH[idx] = h8[g];
            *(short8*)&bL[idx] = l8[g];
        }
        // ---- issue next chunk's loads (drain at next convert) ----
        if (ch + 1 < NCHUNK) {
            int kb = kbase0 + (ch + 1) * KCH;
            #pragma unroll
            for (int s = 0; s < 4; ++s) f[s] = vrow[(kb >> 2) + kq * 4 + s];
        }
        __syncthreads();   // buffer p fully staged

        // ---- MFMA phase on buffer p ----
        __builtin_amdgcn_s_setprio(1);
        #pragma unroll
        for (int ks = 0; ks < 2; ++ks) {
            int kf = ks * 32 + lhi * 8;
            short8 Ah[4], Al[4], Bh[4], Bl[4];
            #pragma unroll
            for (int rb = 0; rb < 4; ++rb) {
                int idx = swzidx(wr * 64 + rb * 16 + llo, kf);
                Ah[rb] = *(const short8*)&bH[idx];
                Al[rb] = *(const short8*)&bL[idx];
            }
            #pragma unroll
            for (int cb = 0; cb < 4; ++cb) {
                int idx = swzidx(wc * 64 + cb * 16 + llo, kf);
                Bh[cb] = *(const short8*)&bH[idx];
                Bl[cb] = *(const short8*)&bL[idx];
            }
            #pragma unroll
            for (int rb = 0; rb < 4; ++rb)
                #pragma unroll
                for (int cb = 0; cb < 4; ++cb) {
                    acc[rb][cb] = __builtin_amdgcn_mfma_f32_16x16x32_bf16(Ah[rb], Bh[cb], acc[rb][cb], 0, 0, 0);
                    acc[rb][cb] = __builtin_amdgcn_mfma_f32_16x16x32_bf16(Ah[rb], Bl[cb], acc[rb][cb], 0, 0, 0);
                    acc[rb][cb] = __builtin_amdgcn_mfma_f32_16x16x32_bf16(Al[rb], Bh[cb], acc[rb][cb], 0, 0, 0);
                }
        }
        __builtin_amdgcn_s_setprio(0);
    }

    psum += __shfl_xor(psum, 1);
    psum += __shfl_xor(psum, 2);
    if (kq == 0) atomicAdd(&pooled[b * CDIM + row], psum);

    #pragma unroll
    for (int rb = 0; rb < 4; ++rb) {
        int r0 = wr * 64 + rb * 16 + lhi * 4;
        #pragma unroll
        for (int cb = 0; cb < 4; ++cb) {
            int c0 = wc * 64 + cb * 16 + llo;
            #pragma unroll
            for (int reg = 0; reg < 4; ++reg)
                atomicAdd(&energy[((size_t)b * CDIM + r0 + reg) * CDIM + c0], acc[rb][cb][reg]);
        }
    }
}

// ---------------- K2: SE MLP -> sigmoid gate ----------------
__global__ __launch_bounds__(256) void se_kernel(const float* __restrict__ pooled,
                                                 const float* __restrict__ w1,
                                                 const float* __restrict__ b1,
                                                 const float* __restrict__ w2,
                                                 const float* __restrict__ b2,
                                                 float* __restrict__ gate) {
    int b = blockIdx.x;
    int t = threadIdx.x;
    __shared__ float p[CDIM];
    __shared__ float hid[RDIM];
    p[t] = pooled[b * CDIM + t] * (1.0f / HW);
    __syncthreads();
    if (t < RDIM) {
        float s = b1[t];
        const float* wr = w1 + t * CDIM;
        for (int k = 0; k < CDIM; ++k) s = fmaf(wr[k], p[k], s);
        hid[t] = s > 0.f ? s : 0.f;
    }
    __syncthreads();
    float s = b2[t];
    const float* wr = w2 + t * RDIM;
    #pragma unroll
    for (int k = 0; k < RDIM; ++k) s = fmaf(wr[k], hid[k], s);
    gate[b * CDIM + t] = 1.0f / (1.0f + expf(-s));
}

// ---------------- K3: row softmax of (rowmax - energy), in place ----------------
__global__ __launch_bounds__(256) void softmax_kernel(float* __restrict__ energy) {
    int row = blockIdx.x;
    float* e = energy + (size_t)row * CDIM;
    int t = threadIdx.x;
    float val = e[t];

    float m = val;
    for (int off = 32; off > 0; off >>= 1) m = fminf(m, __shfl_down(m, off));
    __shared__ float redm[4];
    if ((t & 63) == 0) redm[t >> 6] = m;
    __syncthreads();
    float rowmin = fminf(fminf(redm[0], redm[1]), fminf(redm[2], redm[3]));

    float p = expf(rowmin - val);
    float s = p;
    for (int off = 32; off > 0; off >>= 1) s += __shfl_down(s, off);
    __shared__ float reds[4];
    if ((t & 63) == 0) reds[t >> 6] = s;
    __syncthreads();
    float tot = reds[0] + reds[1] + reds[2] + reds[3];
    e[t] = p / tot;
}

// ---------------- K4: out = gamma * gate * (att @ v) + x  (bf16 MFMA) ----------
__global__ __launch_bounds__(1024) void out_kernel(const float* __restrict__ att,
                                                   const float* __restrict__ x,
                                                   const float* __restrict__ gate,
                                                   const float* __restrict__ gammap,
                                                   float* __restrict__ out) {
    __shared__ __align__(16) char lds[65536];   // A: 32KB @0, B: 32KB @BOFF

    const int t    = threadIdx.x;
    const int lane = t & 63;
    const int wave = t >> 6;
    const int wr   = wave >> 2, wc = wave & 3;
    const int lhi  = lane >> 4, llo = lane & 15;
    const int nblk = blockIdx.x * BN;
    const int b    = blockIdx.y;

    const float* v    = x   + (size_t)b * CDIM * HW;
    const float* attb = att + (size_t)b * CDIM * CDIM;

    f32x4 acc[4][4];
    #pragma unroll
    for (int i = 0; i < 4; ++i)
        #pragma unroll
        for (int j = 0; j < 4; ++j)
            acc[i][j] = (f32x4){0.f, 0.f, 0.f, 0.f};

    float4 va0[2], va1[2], aa[4];

    auto load_chunk = [&](int k0) {
        #pragma unroll
        for (int i = 0; i < 2; ++i) {
            int dd0 = 2 * (wave + 16 * i);
            const float* r0 = v + (size_t)(k0 + dd0) * HW + nblk + lane * 4;
            va0[i] = *(const float4*)r0;
            va1[i] = *(const float4*)(r0 + HW);
        }
        #pragma unroll
        for (int i = 0; i < 4; ++i) {
            int c = (t >> 4) + 64 * i;
            aa[i] = *(const float4*)&attb[(size_t)c * CDIM + k0 + (t & 15) * 4];
        }
    };

    load_chunk(0);

    for (int ch = 0; ch < 4; ++ch) {
        __syncthreads();
        #pragma unroll
        for (int i = 0; i < 2; ++i) {
            int dd0 = 2 * (wave + 16 * i);
            const float* f0 = (const float*)&va0[i];
            const float* f1 = (const float*)&va1[i];
            #pragma unroll
            for (int j = 0; j < 4; ++j) {
                int n = lane * 4 + j;
                *(unsigned*)(lds + BOFF + bofs(n, dd0)) = pack2(f0[j], f1[j]);
            }
        }
        #pragma unroll
        for (int i = 0; i < 4; ++i) {
            int c = (t >> 4) + 64 * i;
            const float* fa = (const float*)&aa[i];
            short4_t h = { (short)bf16_rne(fa[0]), (short)bf16_rne(fa[1]),
                           (short)bf16_rne(fa[2]), (short)bf16_rne(fa[3]) };
            *(short4_t*)(lds + bofs(c, (t & 15) * 4)) = h;
        }
        __syncthreads();

        if (ch < 3) load_chunk((ch + 1) * BK);

        #pragma unroll
        for (int ks = 0; ks < 2; ++ks) {
            int kb = ks * 32 + lhi * 8;
            short8 Af[4], Bf[4];
            #pragma unroll
            for (int rb = 0; rb < 4; ++rb)
                Af[rb] = *(const short8*)(lds + bofs(wr * 64 + rb * 16 + llo, kb));
            #pragma unroll
            for (int cb = 0; cb < 4; ++cb)
                Bf[cb] = *(const short8*)(lds + BOFF + bofs(wc * 64 + cb * 16 + llo, kb));
            #pragma unroll
            for (int rb = 0; rb < 4; ++rb)
                #pragma unroll
                for (int cb = 0; cb < 4; ++cb)
                    acc[rb][cb] = __builtin_amdgcn_mfma_f32_16x16x32_bf16(Af[rb], Bf[cb], acc[rb][cb], 0, 0, 0);
        }
    }

    float gm = gammap[0];
    #pragma unroll
    for (int rb = 0; rb < 4; ++rb) {
        #pragma unroll
        for (int r = 0; r < 4; ++r) {
            int c = wr * 64 + rb * 16 + lhi * 4 + r;
            float g = gm * gate[b * CDIM + c];
            size_t rowbase = ((size_t)b * CDIM + c) * HW + nblk;
            #pragma unroll
            for (int cb = 0; cb < 4; ++cb) {
                int n = wc * 64 + cb * 16 + llo;
                out[rowbase + n] = fmaf(acc[rb][cb][r], g, x[rowbase + n]);
            }
        }
    }
}

extern "C" void kernel_launch(void* const* d_in, const int* in_sizes, int n_in,
                              void* d_out, int out_size, void* d_ws, size_t ws_size,
                              hipStream_t stream) {
    const float* x     = (const float*)d_in[0];
    const float* gamma = (const float*)d_in[1];
    const float* w1    = (const float*)d_in[2];
    const float* b1    = (const float*)d_in[3];
    const float* w2    = (const float*)d_in[4];
    const float* b2    = (const float*)d_in[5];
    float* out = (float*)d_out;

    float* energy = (float*)d_ws;                                // B*C*C = 4 MB
    float* pooled = energy + (size_t)BATCH * CDIM * CDIM;
    float* gate   = pooled + BATCH * CDIM;

    hipMemsetAsync(energy, 0, (size_t)BATCH * CDIM * CDIM * sizeof(float), stream);
    hipMemsetAsync(pooled, 0, (size_t)BATCH * CDIM * sizeof(float), stream);
    gram_kernel<<<dim3(SPLITS, BATCH), 1024, 0, stream>>>(x, energy, pooled);
    se_kernel<<<BATCH, 256, 0, stream>>>(pooled, w1, b1, w2, b2, gate);
    softmax_kernel<<<BATCH * CDIM, 256, 0, stream>>>(energy);
    out_kernel<<<dim3(HW / BN, BATCH), 1024, 0, stream>>>(energy, x, gate, gamma, out);
}